// Round 19
// baseline (2838.286 us; speedup 1.0000x reference)
//
#include <hip/hip_runtime.h>
#include <hip/hip_bf16.h>
#include <math.h>
#include <stdint.h>

#define D_MODEL 768
#define T_SEQ   1024
#define B_BATCH 8
#define NHEAD   12
#define HDIM    64
#define NLAYER  8

typedef unsigned short u16;
typedef __attribute__((ext_vector_type(8))) short bf16x8;
typedef __attribute__((ext_vector_type(4))) float f32x4;
typedef __attribute__((ext_vector_type(4))) uint32_t u32x4;

static constexpr size_t BTD  = (size_t)B_BATCH * T_SEQ * D_MODEL;  // 6291456
static constexpr int    ROWS = B_BATCH * T_SEQ;                    // 8192
static constexpr float  EPSF = 1.1920928955078125e-07f;            // FLT_EPSILON

// ---------------------------------------------------------------- helpers

__device__ __forceinline__ u16 f2bf(float x) {
    __hip_bfloat16 h = __float2bfloat16(x);
    return __builtin_bit_cast(u16, h);
}
__device__ __forceinline__ float bf2f(u16 u) {
    __hip_bfloat16 h = __builtin_bit_cast(__hip_bfloat16, u);
    return __bfloat162float(h);
}
__device__ __forceinline__ void split_bf(float x, u16& hi, u16& lo) {
    hi = f2bf(x);
    lo = f2bf(x - bf2f(hi));
}
__device__ __forceinline__ uint32_t cvt_pk_bf16(float a, float b) {
    uint32_t r;
    asm("v_cvt_pk_bf16_f32 %0, %1, %2" : "=v"(r) : "v"(a), "v"(b));
    return r;
}
__device__ __forceinline__ f32x4 mfma16(bf16x8 a, bf16x8 b, f32x4 c) {
    return __builtin_amdgcn_mfma_f32_16x16x32_bf16(a, b, c, 0, 0, 0);
}

// async global->LDS, 16B/lane; LDS dest wave-uniform base (HW adds lane*16)
__device__ __forceinline__ void gl_lds16(const void* g, void* l) {
    auto gp = reinterpret_cast<const __attribute__((address_space(1))) char*>(
        reinterpret_cast<uintptr_t>(g));
    auto lp = reinterpret_cast<__attribute__((address_space(3))) char*>(
        static_cast<uint32_t>(reinterpret_cast<uintptr_t>(l)));
    __builtin_amdgcn_global_load_lds(gp, lp, 16, 0, 0);
}

__device__ __forceinline__ float block_reduce_sum(float v, float* sbuf) {
    #pragma unroll
    for (int off = 32; off > 0; off >>= 1) v += __shfl_down(v, off);
    __syncthreads();
    if ((threadIdx.x & 63) == 0) sbuf[threadIdx.x >> 6] = v;
    __syncthreads();
    return sbuf[0] + sbuf[1] + sbuf[2] + sbuf[3];
}

// tanh-gelu via exp: 0.5x(1+tanh(z)) = x - x/(exp(2z)+1); exact at +-inf
__device__ __forceinline__ float gelu_fast(float x) {
    float z = 0.7978845608028654f * (x + 0.044715f * x * x * x);
    float e = __expf(2.f * z);
    return x - x / (e + 1.f);
}

// ------------------------------------------------- aggregate + rmsnorm fuse
// V-list = N UNIQUE buffers; buffer 0 (x_init) has softmax multiplicity 2.
template<int N>
__global__ __launch_bounds__(256)
void agg_norm_kernel(const float* __restrict__ v0, const float* __restrict__ v1,
                     const float* __restrict__ v2, const float* __restrict__ v3,
                     const float* __restrict__ v4,
                     const float* __restrict__ q,  const float* __restrict__ lns,
                     u16* __restrict__ xh) {
    __shared__ float sbuf[4];
    const float* V[5] = {v0, v1, v2, v3, v4};
    const size_t row = blockIdx.x;
    const int tid = threadIdx.x;

    float outv[3];
    if constexpr (N == 1) {
        #pragma unroll
        for (int j = 0; j < 3; ++j) outv[j] = v0[row * D_MODEL + tid + j * 256];
    } else {
        float qv[3];
        #pragma unroll
        for (int j = 0; j < 3; ++j) qv[j] = q[tid + j * 256];

        float vv[N][3];
        float logits[N];
        #pragma unroll
        for (int i = 0; i < N; ++i) {
            const float* vr = V[i] + row * D_MODEL;
            float ssq = 0.f, qd = 0.f;
            #pragma unroll
            for (int j = 0; j < 3; ++j) {
                float x = vr[tid + j * 256];
                vv[i][j] = x;
                ssq = fmaf(x, x, ssq);
                qd  = fmaf(qv[j], x, qd);
            }
            float S  = block_reduce_sum(ssq, sbuf);
            float Qd = block_reduce_sum(qd,  sbuf);
            logits[i] = Qd * rsqrtf(S * (1.f / 768.f) + EPSF);
        }
        float mx = logits[0];
        #pragma unroll
        for (int i = 1; i < N; ++i) mx = fmaxf(mx, logits[i]);
        float w[N];
        #pragma unroll
        for (int i = 0; i < N; ++i) w[i] = __expf(logits[i] - mx);
        w[0] *= 2.f;                       // x_init multiplicity 2
        float wsum = 0.f;
        #pragma unroll
        for (int i = 0; i < N; ++i) wsum += w[i];
        float inv = 1.f / wsum;
        outv[0] = outv[1] = outv[2] = 0.f;
        #pragma unroll
        for (int i = 0; i < N; ++i) {
            float wi = w[i] * inv;
            #pragma unroll
            for (int j = 0; j < 3; ++j) outv[j] = fmaf(wi, vv[i][j], outv[j]);
        }
    }
    float ssq = 0.f;
    #pragma unroll
    for (int j = 0; j < 3; ++j) ssq = fmaf(outv[j], outv[j], ssq);
    float S2 = block_reduce_sum(ssq, sbuf);
    float scale = lns[0] * rsqrtf(S2 * (1.f / 768.f) + EPSF);
    #pragma unroll
    for (int j = 0; j < 3; ++j)
        xh[row * D_MODEL + tid + j * 256] = f2bf(outv[j] * scale);
}

// ---------------------------------------------- fused per-layer weight transpose
__global__ __launch_bounds__(256)
void transpose_all(const float* __restrict__ Wqkv, const float* __restrict__ Wo,
                   const float* __restrict__ Wm1,  const float* __restrict__ Wm2,
                   u16* __restrict__ T0, u16* __restrict__ T1,
                   u16* __restrict__ T2, u16* __restrict__ T3) {
    const int id = blockIdx.x;
    const float* W; u16* Th; int K, N, t;
    if (id < 1728)      { W = Wqkv; Th = T0; K = 768;  N = 2304; t = id; }
    else if (id < 2304) { W = Wo;   Th = T1; K = 768;  N = 768;  t = id - 1728; }
    else if (id < 4608) { W = Wm1;  Th = T2; K = 768;  N = 3072; t = id - 2304; }
    else                { W = Wm2;  Th = T3; K = 3072; N = 768;  t = id - 4608; }
    const int nk = K >> 5;
    const int bk = (t % nk) * 32, bn = (t / nk) * 32;

    __shared__ float tt[32][33];
    const int r = threadIdx.x >> 3, c4 = (threadIdx.x & 7) * 4;
    float4 v = *(const float4*)&W[(size_t)(bk + r) * N + bn + c4];
    tt[r][c4 + 0] = v.x; tt[r][c4 + 1] = v.y; tt[r][c4 + 2] = v.z; tt[r][c4 + 3] = v.w;
    __syncthreads();
    u16 h[4];
    #pragma unroll
    for (int j = 0; j < 4; ++j) h[j] = f2bf(tt[c4 + j][r]);
    size_t o = (size_t)(bn + r) * K + bk + c4;
    *(uint2*)&Th[o] = make_uint2((uint32_t)h[0] | ((uint32_t)h[1] << 16),
                                 (uint32_t)h[2] | ((uint32_t)h[3] << 16));
}

// ------------------------------------------------- bf16 MFMA GEMM (1-term)
// C[M,N] = Ah[M,K] @ Bh^T (B given as [N][K]).
// Prefetch-pipelined: LDS double-buffer, counted vmcnt + raw barriers.
// EPI: 1 = gelu -> bf16, 2 = Cf += scale[n]*acc, 4 = Cf = scale[n]*acc,
//      3 = scatter qkv (q*0.125): Q hi/lo + K hi row-major head-major,
//          V hi DIRECTLY TRANSPOSED into vth [bh][64][1024]
template<int EPI, int BN>
__global__ __launch_bounds__(256)
void gemm_bf1(const u16* __restrict__ Ah, const u16* __restrict__ Bh,
              float* __restrict__ Cf, u16* __restrict__ Ch,
              const float* __restrict__ scale, int M, int N, int K,
              u16* __restrict__ Qh, u16* __restrict__ Ql,
              u16* __restrict__ Kh, u16* __restrict__ Vt) {
    constexpr int NJ = BN / 32;
    constexpr int BUF_U16 = 4096 + BN * 32;      // per-buffer size (u16)
    __shared__ u16 smem[2 * BUF_U16];

    // XCD-contiguous remap (nwg always % 8 == 0)
    const int gx = gridDim.x, gy = gridDim.y;
    const int nwg = gx * gy;
    const int lin = blockIdx.y * gx + blockIdx.x;
    const int wg  = (lin & 7) * (nwg >> 3) + (lin >> 3);
    const int bn  = (wg % gx) * BN;
    const int bm  = (wg / gx) << 7;

    const int tid = threadIdx.x;
    const int w = tid >> 6, l = tid & 63;
    const int wr = w >> 1, wc = w & 1;

    const int grow = tid >> 2;
    const int gcol = (((tid & 3) ^ ((tid >> 3) & 3)) << 3);
    const size_t aoff0 = (size_t)(bm + grow) * K + gcol;
    const size_t boff0 = (size_t)(bn + grow) * K + gcol;
    const size_t s64 = (size_t)64 * K;
    char* sb0 = (char*)smem;
    char* sb1 = (char*)smem + 2 * BUF_U16;       // bytes
    const uint32_t wq = (uint32_t)w << 10;

    auto stage = [&](char* sbuf, int k0) {
        gl_lds16(Ah + aoff0 + k0,       sbuf + 0    + wq);
        gl_lds16(Ah + aoff0 + s64 + k0, sbuf + 4096 + wq);
        gl_lds16(Bh + boff0 + k0,       sbuf + 8192 + wq);
        if constexpr (BN == 128)
            gl_lds16(Bh + boff0 + s64 + k0, sbuf + 12288 + wq);
    };

    f32x4 acc[4][NJ] = {};

    const int key8 = (((l & 15) >> 1) & 3) << 3;
    const int kswz = ((l >> 4) << 3) ^ key8;
    const int arow = wr * 64 + (l & 15);
    const int brow = wc * (BN / 2) + (l & 15);
    const int nk = K >> 5;

    stage(sb0, 0);
    for (int kt = 0; kt < nk; ++kt) {
        char* cur = (kt & 1) ? sb1 : sb0;
        char* nxt = (kt & 1) ? sb0 : sb1;
        if (kt + 1 < nk) {
            stage(nxt, (kt + 1) << 5);
            if constexpr (BN == 128)
                asm volatile("s_waitcnt vmcnt(4)\n\ts_barrier" ::: "memory");
            else
                asm volatile("s_waitcnt vmcnt(3)\n\ts_barrier" ::: "memory");
        } else {
            asm volatile("s_waitcnt vmcnt(0)\n\ts_barrier" ::: "memory");
        }
        __builtin_amdgcn_sched_barrier(0);

        const u16* bu = (const u16*)cur;
        bf16x8 ah[4], bh4[NJ];
        #pragma unroll
        for (int i = 0; i < 4; ++i)
            ah[i] = *(const bf16x8*)&bu[(arow + i * 16) * 32 + kswz];
        #pragma unroll
        for (int j = 0; j < NJ; ++j)
            bh4[j] = *(const bf16x8*)&bu[4096 + (brow + j * 16) * 32 + kswz];
        asm volatile("s_waitcnt lgkmcnt(0)" ::: "memory");
        __builtin_amdgcn_sched_barrier(0);
        asm volatile("s_barrier" ::: "memory");   // all waves done reading cur

        #pragma unroll
        for (int i = 0; i < 4; ++i) {
            #pragma unroll
            for (int j = 0; j < NJ; ++j)
                acc[i][j] = mfma16(ah[i], bh4[j], acc[i][j]);
        }
    }

    // C/D frag: col = lane&15, row = (lane>>4)*4 + reg
    const int crow0 = bm + wr * 64 + ((l >> 4) << 2);
    const int ccol0 = bn + wc * (BN / 2) + (l & 15);
    #pragma unroll
    for (int i = 0; i < 4; ++i) {
        #pragma unroll
        for (int j = 0; j < NJ; ++j) {
            const int col = ccol0 + j * 16;
            #pragma unroll
            for (int r = 0; r < 4; ++r) {
                const int row = crow0 + i * 16 + r;
                const size_t o = (size_t)row * N + col;
                float v = acc[i][j][r];
                if (EPI == 1) {
                    Ch[o] = f2bf(gelu_fast(v));
                } else if (EPI == 2) {
                    Cf[o] += scale[col] * v;
                } else if (EPI == 4) {
                    Cf[o] = scale[col] * v;
                } else if (EPI == 3) {
                    const int which = (col >= 1536) ? 2 : ((col >= 768) ? 1 : 0);
                    const int hcol = col - which * 768;
                    const size_t bhd = (size_t)((row >> 10) * NHEAD + (hcol >> 6));
                    if (which == 0) {
                        const size_t dst = (bhd * 1024 + (row & 1023)) * 64 + (hcol & 63);
                        v *= 0.125f;
                        u16 hi, lo;
                        split_bf(v, hi, lo);
                        Qh[dst] = hi; Ql[dst] = lo;
                    } else if (which == 1) {
                        const size_t dst = (bhd * 1024 + (row & 1023)) * 64 + (hcol & 63);
                        Kh[dst] = f2bf(v);
                    } else {
                        // direct transposed V: vth[bh][d][t]
                        const size_t dst = (bhd * 64 + (hcol & 63)) * 1024 + (row & 1023);
                        Vt[dst] = f2bf(v);
                    }
                }
            }
        }
    }
}

// --------------------------------------------------- MFMA flash attention
// (r15-proven) Paired q-tiles {p, 15-p} share one K/V fragment stream from
// GLOBAL (L2-resident); K/V register double-buffer; K hi-only
// (S = Kh*(Qh+Ql)); defer-max (THR=8); ctx single bf16; shuffle P redistrib.
__global__ __launch_bounds__(256, 3)
void flash16(const u16* __restrict__ qh, const u16* __restrict__ ql,
             const u16* __restrict__ kh, const u16* __restrict__ vth,
             u16* __restrict__ ch) {
    const int id = blockIdx.x;
    const int r8 = id & 7, s = id >> 3;
    const int bh = r8 + 8 * (s >> 3);
    const int p  = s & 7;
    const int hh = bh % NHEAD, bb = bh / NHEAD;
    const int tid = threadIdx.x, w = tid >> 6, l = tid & 63;
    const int lq = l & 15, lg = l >> 4;
    const size_t hb = (size_t)bh << 16;

    const int wqA = p * 64 + w * 16;
    const int wqB = (15 - p) * 64 + w * 16;
    const int qA = wqA + lq, qB = wqB + lq;

    bf16x8 qA0, qA1, qA2, qA3, qB0, qB1, qB2, qB3;
    {
        const size_t qa = hb + ((size_t)qA << 6) + lg * 8;
        qA0 = *(const bf16x8*)(qh + qa);       qA1 = *(const bf16x8*)(ql + qa);
        qA2 = *(const bf16x8*)(qh + qa + 32);  qA3 = *(const bf16x8*)(ql + qa + 32);
        const size_t qb = hb + ((size_t)qB << 6) + lg * 8;
        qB0 = *(const bf16x8*)(qh + qb);       qB1 = *(const bf16x8*)(ql + qb);
        qB2 = *(const bf16x8*)(qh + qb + 32);  qB3 = *(const bf16x8*)(ql + qb + 32);
    }

    f32x4 oA[4] = {}, oB[4] = {};
    float mA = -30000.f, lsA = 0.f, mB = -30000.f, lsB = 0.f;
    const int ntiles = 32 - 2 * p;              // always even
    const int src0 = 32 * (lg & 1) + lq, src1 = src0 + 16;
    const bool hiHalf = lg >= 2;

    bf16x8 KA[4], KB[4], VA[4], VB[4];
    auto loadK = [&](bf16x8 (&K)[4], int k0) {
        const size_t kb0 = hb + (size_t)(k0 + lq) * 64 + lg * 8;
        const size_t kb1 = kb0 + 16 * 64;
        K[0] = *(const bf16x8*)(kh + kb0);
        K[1] = *(const bf16x8*)(kh + kb0 + 32);
        K[2] = *(const bf16x8*)(kh + kb1);
        K[3] = *(const bf16x8*)(kh + kb1 + 32);
    };
    auto loadV = [&](bf16x8 (&V)[4], int k0) {
        #pragma unroll
        for (int dt = 0; dt < 4; ++dt) {
            const size_t vb = hb + (size_t)(dt * 16 + lq) * 1024 + k0 + lg * 8;
            V[dt] = *(const bf16x8*)(vth + vb);
        }
    };

    auto path = [&](bf16x8 (&Kc)[4], bf16x8 (&vf)[4], int k0, int wqX, int qX,
                    bf16x8 q0, bf16x8 q1, bf16x8 q2, bf16x8 q3,
                    float& mX, float& lsX, f32x4 (&oX)[4]) {
        f32x4 s0 = {}, s1 = {};
        s0 = mfma16(Kc[0], q0, s0); s0 = mfma16(Kc[0], q1, s0);
        s0 = mfma16(Kc[1], q2, s0); s0 = mfma16(Kc[1], q3, s0);
        s1 = mfma16(Kc[2], q0, s1); s1 = mfma16(Kc[2], q1, s1);
        s1 = mfma16(Kc[3], q2, s1); s1 = mfma16(Kc[3], q3, s1);
        if (k0 + 31 > wqX) {
            #pragma unroll
            for (int r = 0; r < 4; ++r) {
                if (k0 + 4 * lg + r > qX)      s0[r] = -30000.f;
                if (k0 + 16 + 4 * lg + r > qX) s1[r] = -30000.f;
            }
        }
        float tmloc = fmaxf(fmaxf(fmaxf(s0[0], s0[1]), fmaxf(s0[2], s0[3])),
                            fmaxf(fmaxf(s1[0], s1[1]), fmaxf(s1[2], s1[3])));
        if (__any(tmloc > mX + 8.f)) {
            float tm = fmaxf(tmloc, __shfl_xor(tmloc, 16));
            tm = fmaxf(tm, __shfl_xor(tm, 32));
            const float mnew = fmaxf(mX, tm);
            const float fac = __expf(mX - mnew);
            mX = mnew;
            lsX *= fac;
            #pragma unroll
            for (int dt = 0; dt < 4; ++dt) {
                oX[dt][0] *= fac; oX[dt][1] *= fac;
                oX[dt][2] *= fac; oX[dt][3] *= fac;
            }
        }
        float ps = 0.f;
        #pragma unroll
        for (int r = 0; r < 4; ++r) {
            s0[r] = __expf(s0[r] - mX); ps += s0[r];
            s1[r] = __expf(s1[r] - mX); ps += s1[r];
        }
        lsX += ps;
        const uint32_t wA0 = cvt_pk_bf16(s0[0], s0[1]);
        const uint32_t wA1 = cvt_pk_bf16(s0[2], s0[3]);
        const uint32_t wB0 = cvt_pk_bf16(s1[0], s1[1]);
        const uint32_t wB1 = cvt_pk_bf16(s1[2], s1[3]);
        const uint32_t a0 = (uint32_t)__shfl((int)wA0, src0);
        const uint32_t b0 = (uint32_t)__shfl((int)wB0, src0);
        const uint32_t a1 = (uint32_t)__shfl((int)wA1, src0);
        const uint32_t b1 = (uint32_t)__shfl((int)wB1, src0);
        const uint32_t a2 = (uint32_t)__shfl((int)wA0, src1);
        const uint32_t b2 = (uint32_t)__shfl((int)wB0, src1);
        const uint32_t a3 = (uint32_t)__shfl((int)wA1, src1);
        const uint32_t b3 = (uint32_t)__shfl((int)wB1, src1);
        u32x4 pw = { hiHalf ? b0 : a0, hiHalf ? b1 : a1,
                     hiHalf ? b2 : a2, hiHalf ? b3 : a3 };
        const bf16x8 pb = __builtin_bit_cast(bf16x8, pw);
        #pragma unroll
        for (int dt = 0; dt < 4; ++dt)
            oX[dt] = mfma16(vf[dt], pb, oX[dt]);
    };

    auto step = [&](bf16x8 (&Kc)[4], bf16x8 (&Vc)[4],
                    bf16x8 (&Kn)[4], bf16x8 (&Vn)[4], int kt) {
        const int k0 = kt * 32;
        const int ktn = (kt + 1 < ntiles) ? kt + 1 : kt;
        loadK(Kn, ktn * 32);
        loadV(Vn, ktn * 32);
        if (k0 <= wqB + 15)
            path(Kc, Vc, k0, wqB, qB, qB0, qB1, qB2, qB3, mB, lsB, oB);
        if (k0 <= wqA + 15)
            path(Kc, Vc, k0, wqA, qA, qA0, qA1, qA2, qA3, mA, lsA, oA);
    };

    loadK(KA, 0);
    loadV(VA, 0);
    for (int kt = 0; kt < ntiles; kt += 2) {
        step(KA, VA, KB, VB, kt);
        step(KB, VB, KA, VA, kt + 1);
    }

    lsA += __shfl_xor(lsA, 16); lsA += __shfl_xor(lsA, 32);
    lsB += __shfl_xor(lsB, 16); lsB += __shfl_xor(lsB, 32);
    const float invA = 1.f / lsA, invB = 1.f / lsB;
    const size_t cbA = ((size_t)(bb * 1024 + qA)) * 768 + hh * 64;
    const size_t cbB = ((size_t)(bb * 1024 + qB)) * 768 + hh * 64;
    #pragma unroll
    for (int dt = 0; dt < 4; ++dt) {
        u16 h4[4];
        #pragma unroll
        for (int r = 0; r < 4; ++r) h4[r] = f2bf(oA[dt][r] * invA);
        size_t co = cbA + dt * 16 + 4 * lg;
        *(uint2*)&ch[co] = make_uint2((uint32_t)h4[0] | ((uint32_t)h4[1] << 16),
                                      (uint32_t)h4[2] | ((uint32_t)h4[3] << 16));
        #pragma unroll
        for (int r = 0; r < 4; ++r) h4[r] = f2bf(oB[dt][r] * invB);
        co = cbB + dt * 16 + 4 * lg;
        *(uint2*)&ch[co] = make_uint2((uint32_t)h4[0] | ((uint32_t)h4[1] << 16),
                                      (uint32_t)h4[2] | ((uint32_t)h4[3] << 16));
    }
}

// ------------------------------------------------------------------- host

extern "C" void kernel_launch(void* const* d_in, const int* in_sizes, int n_in,
                              void* d_out, int out_size, void* d_ws, size_t ws_size,
                              hipStream_t stream) {
    const float* x0     = (const float*)d_in[0];
    const float* aproj  = (const float*)d_in[1];
    const float* mproj  = (const float*)d_in[2];
    const float* Wqkv   = (const float*)d_in[3];
    const float* Wo     = (const float*)d_in[4];
    const float* Wm1    = (const float*)d_in[5];
    const float* Wm2    = (const float*)d_in[6];
    const float* ascale = (const float*)d_in[7];
    const float* mscale = (const float*)d_in[8];
    const float* lns    = (const float*)d_in[9];
    float* out = (float*)d_out;
    char*  base = (char*)d_ws;

    float* p1  = (float*)base;
    float* p2  = p1 + BTD;
    float* p3  = p2 + BTD;
    u16*   xnh = (u16*)(base + 12 * BTD);
    u16*   wt0 = (u16*)(base + 14 * BTD);
    u16*   wt1 = wt0 + (size_t)2304 * 768;
    u16*   wt2 = wt1 + (size_t)768 * 768;
    u16*   wt3 = wt2 + (size_t)3072 * 768;
    char*  QB  = (char*)(wt3 + (size_t)768 * 3072);
    u16* qh   = (u16*)QB;        // slot 0
    u16* ql   = qh  + BTD;       // slot 1
    u16* kh   = ql  + BTD;       // slot 2
    u16* ctxh = kh  + BTD;       // slot 3 (flash output)
    u16* vth  = ctxh + BTD;      // slot 4 (V written transposed by QKV epi)
    u16* midh = qh;              // spans slots 0-3 (q/k/ctx dead after Wo)

    float* pb[3] = {p1, p2, p3};
    const float* L[5] = {x0, nullptr, nullptr, nullptr, nullptr};
    int nL = 1;
    float* partial_w = nullptr;
    int pidx = 0;

    auto launch_agg = [&](const float* qvec, const float* lnsl) {
        const float* a = L[0];
        const float* b = (nL > 1) ? L[1] : nullptr;
        const float* c = (nL > 2) ? L[2] : nullptr;
        const float* d = (nL > 3) ? L[3] : nullptr;
        const float* e = (nL > 4) ? L[4] : nullptr;
        switch (nL) {
        case 1: agg_norm_kernel<1><<<dim3(ROWS), 256, 0, stream>>>(a, b, c, d, e, qvec, lnsl, xnh); break;
        case 2: agg_norm_kernel<2><<<dim3(ROWS), 256, 0, stream>>>(a, b, c, d, e, qvec, lnsl, xnh); break;
        case 3: agg_norm_kernel<3><<<dim3(ROWS), 256, 0, stream>>>(a, b, c, d, e, qvec, lnsl, xnh); break;
        case 4: agg_norm_kernel<4><<<dim3(ROWS), 256, 0, stream>>>(a, b, c, d, e, qvec, lnsl, xnh); break;
        default: agg_norm_kernel<5><<<dim3(ROWS), 256, 0, stream>>>(a, b, c, d, e, qvec, lnsl, xnh); break;
        }
    };

    for (int l = 0; l < NLAYER; ++l) {
        // ---- all 4 weight transposes in one dispatch
        transpose_all<<<dim3(6912), 256, 0, stream>>>(
            Wqkv + (size_t)l * D_MODEL * 3 * D_MODEL,
            Wo   + (size_t)l * D_MODEL * D_MODEL,
            Wm1  + (size_t)l * D_MODEL * 4 * D_MODEL,
            Wm2  + (size_t)l * 4 * D_MODEL * D_MODEL,
            wt0, wt1, wt2, wt3);

        // ---- attention-path aggregate (reads OLD partial) -> xn (bf16)
        launch_agg(aproj + (size_t)l * D_MODEL, lns + l);

        // ---- block boundary (no fill: Wo EPI=4 initializes the new partial)
        const bool boundary = ((l & 1) == 0);
        if (boundary) {
            float* np = (pidx < 3) ? pb[pidx] : out;
            ++pidx;
            partial_w = np;
            L[nL++] = np;
        }

        // ---- QKV GEMM -> q (hi/lo), k (hi) row-major; V written transposed
        gemm_bf1<3, 128><<<dim3(3 * D_MODEL / 128, ROWS / 128), 256, 0, stream>>>(
            xnh, wt0, nullptr, nullptr, nullptr,
            ROWS, 3 * D_MODEL, D_MODEL, qh, ql, kh, vth);

        // ---- flash attention -> ctx (single bf16)
        flash16<<<dim3(768), 256, 0, stream>>>(qh, ql, kh, vth, ctxh);

        // ---- Wo GEMM: partial (=|+=) attn_scale * (ctx @ Wo)
        if (boundary)
            gemm_bf1<4, 64><<<dim3(D_MODEL / 64, ROWS / 128), 256, 0, stream>>>(
                ctxh, wt1, partial_w, nullptr,
                ascale + (size_t)l * D_MODEL, ROWS, D_MODEL, D_MODEL,
                nullptr, nullptr, nullptr, nullptr);
        else
            gemm_bf1<2, 64><<<dim3(D_MODEL / 64, ROWS / 128), 256, 0, stream>>>(
                ctxh, wt1, partial_w, nullptr,
                ascale + (size_t)l * D_MODEL, ROWS, D_MODEL, D_MODEL,
                nullptr, nullptr, nullptr, nullptr);

        // ---- mlp-path aggregate (reads NEW partial) -> xn (bf16)
        launch_agg(mproj + (size_t)l * D_MODEL, lns + l);

        // ---- MLP: mid = gelu(xn @ Wm1) bf16; partial += mscale*(mid @ Wm2)
        gemm_bf1<1, 128><<<dim3(4 * D_MODEL / 128, ROWS / 128), 256, 0, stream>>>(
            xnh, wt2, nullptr, midh,
            nullptr, ROWS, 4 * D_MODEL, D_MODEL,
            nullptr, nullptr, nullptr, nullptr);
        gemm_bf1<2, 64><<<dim3(D_MODEL / 64, ROWS / 128), 256, 0, stream>>>(
            midh, wt3, partial_w, nullptr,
            mscale + (size_t)l * D_MODEL, ROWS, D_MODEL, 4 * D_MODEL,
            nullptr, nullptr, nullptr, nullptr);
    }
}

// Round 20
// 2777.692 us; speedup vs baseline: 1.0218x; 1.0218x over previous
//
#include <hip/hip_runtime.h>
#include <hip/hip_bf16.h>
#include <math.h>
#include <stdint.h>

#define D_MODEL 768
#define T_SEQ   1024
#define B_BATCH 8
#define NHEAD   12
#define HDIM    64
#define NLAYER  8

typedef unsigned short u16;
typedef __attribute__((ext_vector_type(8))) short bf16x8;
typedef __attribute__((ext_vector_type(4))) float f32x4;
typedef __attribute__((ext_vector_type(4))) uint32_t u32x4;

static constexpr size_t BTD  = (size_t)B_BATCH * T_SEQ * D_MODEL;  // 6291456
static constexpr int    ROWS = B_BATCH * T_SEQ;                    // 8192
static constexpr float  EPSF = 1.1920928955078125e-07f;            // FLT_EPSILON

// ---------------------------------------------------------------- helpers

__device__ __forceinline__ u16 f2bf(float x) {
    __hip_bfloat16 h = __float2bfloat16(x);
    return __builtin_bit_cast(u16, h);
}
__device__ __forceinline__ float bf2f(u16 u) {
    __hip_bfloat16 h = __builtin_bit_cast(__hip_bfloat16, u);
    return __bfloat162float(h);
}
__device__ __forceinline__ void split_bf(float x, u16& hi, u16& lo) {
    hi = f2bf(x);
    lo = f2bf(x - bf2f(hi));
}
__device__ __forceinline__ uint32_t cvt_pk_bf16(float a, float b) {
    uint32_t r;
    asm("v_cvt_pk_bf16_f32 %0, %1, %2" : "=v"(r) : "v"(a), "v"(b));
    return r;
}
__device__ __forceinline__ f32x4 mfma16(bf16x8 a, bf16x8 b, f32x4 c) {
    return __builtin_amdgcn_mfma_f32_16x16x32_bf16(a, b, c, 0, 0, 0);
}

// async global->LDS, 16B/lane; LDS dest wave-uniform base (HW adds lane*16)
__device__ __forceinline__ void gl_lds16(const void* g, void* l) {
    auto gp = reinterpret_cast<const __attribute__((address_space(1))) char*>(
        reinterpret_cast<uintptr_t>(g));
    auto lp = reinterpret_cast<__attribute__((address_space(3))) char*>(
        static_cast<uint32_t>(reinterpret_cast<uintptr_t>(l)));
    __builtin_amdgcn_global_load_lds(gp, lp, 16, 0, 0);
}

__device__ __forceinline__ float block_reduce_sum(float v, float* sbuf) {
    #pragma unroll
    for (int off = 32; off > 0; off >>= 1) v += __shfl_down(v, off);
    __syncthreads();
    if ((threadIdx.x & 63) == 0) sbuf[threadIdx.x >> 6] = v;
    __syncthreads();
    return sbuf[0] + sbuf[1] + sbuf[2] + sbuf[3];
}

// tanh-gelu via exp: 0.5x(1+tanh(z)) = x - x/(exp(2z)+1); exact at +-inf
__device__ __forceinline__ float gelu_fast(float x) {
    float z = 0.7978845608028654f * (x + 0.044715f * x * x * x);
    float e = __expf(2.f * z);
    return x - x / (e + 1.f);
}

// ------------------------------------------------- aggregate + rmsnorm fuse
// V-list = N UNIQUE buffers; buffer 0 (x_init) has softmax multiplicity 2.
template<int N>
__global__ __launch_bounds__(256)
void agg_norm_kernel(const float* __restrict__ v0, const float* __restrict__ v1,
                     const float* __restrict__ v2, const float* __restrict__ v3,
                     const float* __restrict__ v4,
                     const float* __restrict__ q,  const float* __restrict__ lns,
                     u16* __restrict__ xh) {
    __shared__ float sbuf[4];
    const float* V[5] = {v0, v1, v2, v3, v4};
    const size_t row = blockIdx.x;
    const int tid = threadIdx.x;

    float outv[3];
    if constexpr (N == 1) {
        #pragma unroll
        for (int j = 0; j < 3; ++j) outv[j] = v0[row * D_MODEL + tid + j * 256];
    } else {
        float qv[3];
        #pragma unroll
        for (int j = 0; j < 3; ++j) qv[j] = q[tid + j * 256];

        float vv[N][3];
        float logits[N];
        #pragma unroll
        for (int i = 0; i < N; ++i) {
            const float* vr = V[i] + row * D_MODEL;
            float ssq = 0.f, qd = 0.f;
            #pragma unroll
            for (int j = 0; j < 3; ++j) {
                float x = vr[tid + j * 256];
                vv[i][j] = x;
                ssq = fmaf(x, x, ssq);
                qd  = fmaf(qv[j], x, qd);
            }
            float S  = block_reduce_sum(ssq, sbuf);
            float Qd = block_reduce_sum(qd,  sbuf);
            logits[i] = Qd * rsqrtf(S * (1.f / 768.f) + EPSF);
        }
        float mx = logits[0];
        #pragma unroll
        for (int i = 1; i < N; ++i) mx = fmaxf(mx, logits[i]);
        float w[N];
        #pragma unroll
        for (int i = 0; i < N; ++i) w[i] = __expf(logits[i] - mx);
        w[0] *= 2.f;                       // x_init multiplicity 2
        float wsum = 0.f;
        #pragma unroll
        for (int i = 0; i < N; ++i) wsum += w[i];
        float inv = 1.f / wsum;
        outv[0] = outv[1] = outv[2] = 0.f;
        #pragma unroll
        for (int i = 0; i < N; ++i) {
            float wi = w[i] * inv;
            #pragma unroll
            for (int j = 0; j < 3; ++j) outv[j] = fmaf(wi, vv[i][j], outv[j]);
        }
    }
    float ssq = 0.f;
    #pragma unroll
    for (int j = 0; j < 3; ++j) ssq = fmaf(outv[j], outv[j], ssq);
    float S2 = block_reduce_sum(ssq, sbuf);
    float scale = lns[0] * rsqrtf(S2 * (1.f / 768.f) + EPSF);
    #pragma unroll
    for (int j = 0; j < 3; ++j)
        xh[row * D_MODEL + tid + j * 256] = f2bf(outv[j] * scale);
}

// ---------------------------------------------- fused per-layer weight transpose
__global__ __launch_bounds__(256)
void transpose_all(const float* __restrict__ Wqkv, const float* __restrict__ Wo,
                   const float* __restrict__ Wm1,  const float* __restrict__ Wm2,
                   u16* __restrict__ T0, u16* __restrict__ T1,
                   u16* __restrict__ T2, u16* __restrict__ T3) {
    const int id = blockIdx.x;
    const float* W; u16* Th; int K, N, t;
    if (id < 1728)      { W = Wqkv; Th = T0; K = 768;  N = 2304; t = id; }
    else if (id < 2304) { W = Wo;   Th = T1; K = 768;  N = 768;  t = id - 1728; }
    else if (id < 4608) { W = Wm1;  Th = T2; K = 768;  N = 3072; t = id - 2304; }
    else                { W = Wm2;  Th = T3; K = 3072; N = 768;  t = id - 4608; }
    const int nk = K >> 5;
    const int bk = (t % nk) * 32, bn = (t / nk) * 32;

    __shared__ float tt[32][33];
    const int r = threadIdx.x >> 3, c4 = (threadIdx.x & 7) * 4;
    float4 v = *(const float4*)&W[(size_t)(bk + r) * N + bn + c4];
    tt[r][c4 + 0] = v.x; tt[r][c4 + 1] = v.y; tt[r][c4 + 2] = v.z; tt[r][c4 + 3] = v.w;
    __syncthreads();
    u16 h[4];
    #pragma unroll
    for (int j = 0; j < 4; ++j) h[j] = f2bf(tt[c4 + j][r]);
    size_t o = (size_t)(bn + r) * K + bk + c4;
    *(uint2*)&Th[o] = make_uint2((uint32_t)h[0] | ((uint32_t)h[1] << 16),
                                 (uint32_t)h[2] | ((uint32_t)h[3] << 16));
}

// ---------------------------------------------- V transpose (head-major, hi only)
__global__ __launch_bounds__(256)
void vt_transpose(const u16* __restrict__ vh, u16* __restrict__ vth) {
    __shared__ u16 th[32][36];
    const int bh = blockIdx.z;
    const int t0 = blockIdx.x * 32, d0 = blockIdx.y * 32;
    const int r = threadIdx.x >> 3, c = (threadIdx.x & 7) * 4;
    const size_t ib = ((size_t)(bh << 10) + t0 + r) * 64 + d0 + c;
    *(uint2*)&th[r][c] = *(const uint2*)&vh[ib];
    __syncthreads();
    const size_t ob = ((size_t)(bh << 6) + d0 + r) * 1024 + t0 + c;
    u16 a0 = th[c + 0][r], a1 = th[c + 1][r], a2 = th[c + 2][r], a3 = th[c + 3][r];
    *(uint2*)&vth[ob] = make_uint2((uint32_t)a0 | ((uint32_t)a1 << 16),
                                   (uint32_t)a2 | ((uint32_t)a3 << 16));
}

// ------------------------------------------------- bf16 MFMA GEMM (1-term)
// C[M,N] = Ah[M,K] @ Bh^T (B given as [N][K]).
// Prefetch-pipelined: LDS double-buffer, counted vmcnt + raw barriers.
// EPI: 1 = gelu -> bf16, 2 = Cf += scale[n]*acc, 4 = Cf = scale[n]*acc,
//      3 = scatter qkv (q*0.125) into head-major buffers (Q hi/lo, K/V hi)
template<int EPI, int BN>
__global__ __launch_bounds__(256)
void gemm_bf1(const u16* __restrict__ Ah, const u16* __restrict__ Bh,
              float* __restrict__ Cf, u16* __restrict__ Ch,
              const float* __restrict__ scale, int M, int N, int K,
              u16* __restrict__ Qh, u16* __restrict__ Ql,
              u16* __restrict__ Kh, u16* __restrict__ Vh) {
    constexpr int NJ = BN / 32;
    constexpr int BUF_U16 = 4096 + BN * 32;      // per-buffer size (u16)
    __shared__ u16 smem[2 * BUF_U16];

    // XCD-contiguous remap (nwg always % 8 == 0)
    const int gx = gridDim.x, gy = gridDim.y;
    const int nwg = gx * gy;
    const int lin = blockIdx.y * gx + blockIdx.x;
    const int wg  = (lin & 7) * (nwg >> 3) + (lin >> 3);
    const int bn  = (wg % gx) * BN;
    const int bm  = (wg / gx) << 7;

    const int tid = threadIdx.x;
    const int w = tid >> 6, l = tid & 63;
    const int wr = w >> 1, wc = w & 1;

    const int grow = tid >> 2;
    const int gcol = (((tid & 3) ^ ((tid >> 3) & 3)) << 3);
    const size_t aoff0 = (size_t)(bm + grow) * K + gcol;
    const size_t boff0 = (size_t)(bn + grow) * K + gcol;
    const size_t s64 = (size_t)64 * K;
    char* sb0 = (char*)smem;
    char* sb1 = (char*)smem + 2 * BUF_U16;       // bytes
    const uint32_t wq = (uint32_t)w << 10;

    auto stage = [&](char* sbuf, int k0) {
        gl_lds16(Ah + aoff0 + k0,       sbuf + 0    + wq);
        gl_lds16(Ah + aoff0 + s64 + k0, sbuf + 4096 + wq);
        gl_lds16(Bh + boff0 + k0,       sbuf + 8192 + wq);
        if constexpr (BN == 128)
            gl_lds16(Bh + boff0 + s64 + k0, sbuf + 12288 + wq);
    };

    f32x4 acc[4][NJ] = {};

    const int key8 = (((l & 15) >> 1) & 3) << 3;
    const int kswz = ((l >> 4) << 3) ^ key8;
    const int arow = wr * 64 + (l & 15);
    const int brow = wc * (BN / 2) + (l & 15);
    const int nk = K >> 5;

    stage(sb0, 0);
    for (int kt = 0; kt < nk; ++kt) {
        char* cur = (kt & 1) ? sb1 : sb0;
        char* nxt = (kt & 1) ? sb0 : sb1;
        if (kt + 1 < nk) {
            stage(nxt, (kt + 1) << 5);
            if constexpr (BN == 128)
                asm volatile("s_waitcnt vmcnt(4)\n\ts_barrier" ::: "memory");
            else
                asm volatile("s_waitcnt vmcnt(3)\n\ts_barrier" ::: "memory");
        } else {
            asm volatile("s_waitcnt vmcnt(0)\n\ts_barrier" ::: "memory");
        }
        __builtin_amdgcn_sched_barrier(0);

        const u16* bu = (const u16*)cur;
        bf16x8 ah[4], bh4[NJ];
        #pragma unroll
        for (int i = 0; i < 4; ++i)
            ah[i] = *(const bf16x8*)&bu[(arow + i * 16) * 32 + kswz];
        #pragma unroll
        for (int j = 0; j < NJ; ++j)
            bh4[j] = *(const bf16x8*)&bu[4096 + (brow + j * 16) * 32 + kswz];
        asm volatile("s_waitcnt lgkmcnt(0)" ::: "memory");
        __builtin_amdgcn_sched_barrier(0);
        asm volatile("s_barrier" ::: "memory");   // all waves done reading cur

        #pragma unroll
        for (int i = 0; i < 4; ++i) {
            #pragma unroll
            for (int j = 0; j < NJ; ++j)
                acc[i][j] = mfma16(ah[i], bh4[j], acc[i][j]);
        }
    }

    // C/D frag: col = lane&15, row = (lane>>4)*4 + reg
    const int crow0 = bm + wr * 64 + ((l >> 4) << 2);
    const int ccol0 = bn + wc * (BN / 2) + (l & 15);
    #pragma unroll
    for (int i = 0; i < 4; ++i) {
        #pragma unroll
        for (int j = 0; j < NJ; ++j) {
            const int col = ccol0 + j * 16;
            #pragma unroll
            for (int r = 0; r < 4; ++r) {
                const int row = crow0 + i * 16 + r;
                const size_t o = (size_t)row * N + col;
                float v = acc[i][j][r];
                if (EPI == 1) {
                    Ch[o] = f2bf(gelu_fast(v));
                } else if (EPI == 2) {
                    Cf[o] += scale[col] * v;
                } else if (EPI == 4) {
                    Cf[o] = scale[col] * v;
                } else if (EPI == 3) {
                    const int which = (col >= 1536) ? 2 : ((col >= 768) ? 1 : 0);
                    const int hcol = col - which * 768;
                    const size_t dst = ((size_t)((row >> 10) * NHEAD + (hcol >> 6)) * 1024
                                        + (row & 1023)) * 64 + (hcol & 63);
                    if (which == 0) {
                        v *= 0.125f;
                        u16 hi, lo;
                        split_bf(v, hi, lo);
                        Qh[dst] = hi; Ql[dst] = lo;
                    } else if (which == 1) {
                        Kh[dst] = f2bf(v);
                    } else {
                        Vh[dst] = f2bf(v);
                    }
                }
            }
        }
    }
}

// --------------------------------------------------- MFMA flash attention
// (r15-proven) Paired q-tiles {p, 15-p} share one K/V fragment stream from
// GLOBAL (L2-resident); K/V register double-buffer; K hi-only
// (S = Kh*(Qh+Ql)); defer-max (THR=8); ctx single bf16; shuffle P redistrib.
__global__ __launch_bounds__(256, 3)
void flash16(const u16* __restrict__ qh, const u16* __restrict__ ql,
             const u16* __restrict__ kh, const u16* __restrict__ vth,
             u16* __restrict__ ch) {
    const int id = blockIdx.x;
    const int r8 = id & 7, s = id >> 3;
    const int bh = r8 + 8 * (s >> 3);
    const int p  = s & 7;
    const int hh = bh % NHEAD, bb = bh / NHEAD;
    const int tid = threadIdx.x, w = tid >> 6, l = tid & 63;
    const int lq = l & 15, lg = l >> 4;
    const size_t hb = (size_t)bh << 16;

    const int wqA = p * 64 + w * 16;
    const int wqB = (15 - p) * 64 + w * 16;
    const int qA = wqA + lq, qB = wqB + lq;

    bf16x8 qA0, qA1, qA2, qA3, qB0, qB1, qB2, qB3;
    {
        const size_t qa = hb + ((size_t)qA << 6) + lg * 8;
        qA0 = *(const bf16x8*)(qh + qa);       qA1 = *(const bf16x8*)(ql + qa);
        qA2 = *(const bf16x8*)(qh + qa + 32);  qA3 = *(const bf16x8*)(ql + qa + 32);
        const size_t qb = hb + ((size_t)qB << 6) + lg * 8;
        qB0 = *(const bf16x8*)(qh + qb);       qB1 = *(const bf16x8*)(ql + qb);
        qB2 = *(const bf16x8*)(qh + qb + 32);  qB3 = *(const bf16x8*)(ql + qb + 32);
    }

    f32x4 oA[4] = {}, oB[4] = {};
    float mA = -30000.f, lsA = 0.f, mB = -30000.f, lsB = 0.f;
    const int ntiles = 32 - 2 * p;              // always even
    const int src0 = 32 * (lg & 1) + lq, src1 = src0 + 16;
    const bool hiHalf = lg >= 2;

    bf16x8 KA[4], KB[4], VA[4], VB[4];
    auto loadK = [&](bf16x8 (&K)[4], int k0) {
        const size_t kb0 = hb + (size_t)(k0 + lq) * 64 + lg * 8;
        const size_t kb1 = kb0 + 16 * 64;
        K[0] = *(const bf16x8*)(kh + kb0);
        K[1] = *(const bf16x8*)(kh + kb0 + 32);
        K[2] = *(const bf16x8*)(kh + kb1);
        K[3] = *(const bf16x8*)(kh + kb1 + 32);
    };
    auto loadV = [&](bf16x8 (&V)[4], int k0) {
        #pragma unroll
        for (int dt = 0; dt < 4; ++dt) {
            const size_t vb = hb + (size_t)(dt * 16 + lq) * 1024 + k0 + lg * 8;
            V[dt] = *(const bf16x8*)(vth + vb);
        }
    };

    auto path = [&](bf16x8 (&Kc)[4], bf16x8 (&vf)[4], int k0, int wqX, int qX,
                    bf16x8 q0, bf16x8 q1, bf16x8 q2, bf16x8 q3,
                    float& mX, float& lsX, f32x4 (&oX)[4]) {
        f32x4 s0 = {}, s1 = {};
        s0 = mfma16(Kc[0], q0, s0); s0 = mfma16(Kc[0], q1, s0);
        s0 = mfma16(Kc[1], q2, s0); s0 = mfma16(Kc[1], q3, s0);
        s1 = mfma16(Kc[2], q0, s1); s1 = mfma16(Kc[2], q1, s1);
        s1 = mfma16(Kc[3], q2, s1); s1 = mfma16(Kc[3], q3, s1);
        if (k0 + 31 > wqX) {
            #pragma unroll
            for (int r = 0; r < 4; ++r) {
                if (k0 + 4 * lg + r > qX)      s0[r] = -30000.f;
                if (k0 + 16 + 4 * lg + r > qX) s1[r] = -30000.f;
            }
        }
        float tmloc = fmaxf(fmaxf(fmaxf(s0[0], s0[1]), fmaxf(s0[2], s0[3])),
                            fmaxf(fmaxf(s1[0], s1[1]), fmaxf(s1[2], s1[3])));
        if (__any(tmloc > mX + 8.f)) {
            float tm = fmaxf(tmloc, __shfl_xor(tmloc, 16));
            tm = fmaxf(tm, __shfl_xor(tm, 32));
            const float mnew = fmaxf(mX, tm);
            const float fac = __expf(mX - mnew);
            mX = mnew;
            lsX *= fac;
            #pragma unroll
            for (int dt = 0; dt < 4; ++dt) {
                oX[dt][0] *= fac; oX[dt][1] *= fac;
                oX[dt][2] *= fac; oX[dt][3] *= fac;
            }
        }
        float ps = 0.f;
        #pragma unroll
        for (int r = 0; r < 4; ++r) {
            s0[r] = __expf(s0[r] - mX); ps += s0[r];
            s1[r] = __expf(s1[r] - mX); ps += s1[r];
        }
        lsX += ps;
        const uint32_t wA0 = cvt_pk_bf16(s0[0], s0[1]);
        const uint32_t wA1 = cvt_pk_bf16(s0[2], s0[3]);
        const uint32_t wB0 = cvt_pk_bf16(s1[0], s1[1]);
        const uint32_t wB1 = cvt_pk_bf16(s1[2], s1[3]);
        const uint32_t a0 = (uint32_t)__shfl((int)wA0, src0);
        const uint32_t b0 = (uint32_t)__shfl((int)wB0, src0);
        const uint32_t a1 = (uint32_t)__shfl((int)wA1, src0);
        const uint32_t b1 = (uint32_t)__shfl((int)wB1, src0);
        const uint32_t a2 = (uint32_t)__shfl((int)wA0, src1);
        const uint32_t b2 = (uint32_t)__shfl((int)wB0, src1);
        const uint32_t a3 = (uint32_t)__shfl((int)wA1, src1);
        const uint32_t b3 = (uint32_t)__shfl((int)wB1, src1);
        u32x4 pw = { hiHalf ? b0 : a0, hiHalf ? b1 : a1,
                     hiHalf ? b2 : a2, hiHalf ? b3 : a3 };
        const bf16x8 pb = __builtin_bit_cast(bf16x8, pw);
        #pragma unroll
        for (int dt = 0; dt < 4; ++dt)
            oX[dt] = mfma16(vf[dt], pb, oX[dt]);
    };

    auto step = [&](bf16x8 (&Kc)[4], bf16x8 (&Vc)[4],
                    bf16x8 (&Kn)[4], bf16x8 (&Vn)[4], int kt) {
        const int k0 = kt * 32;
        const int ktn = (kt + 1 < ntiles) ? kt + 1 : kt;
        loadK(Kn, ktn * 32);
        loadV(Vn, ktn * 32);
        if (k0 <= wqB + 15)
            path(Kc, Vc, k0, wqB, qB, qB0, qB1, qB2, qB3, mB, lsB, oB);
        if (k0 <= wqA + 15)
            path(Kc, Vc, k0, wqA, qA, qA0, qA1, qA2, qA3, mA, lsA, oA);
    };

    loadK(KA, 0);
    loadV(VA, 0);
    for (int kt = 0; kt < ntiles; kt += 2) {
        step(KA, VA, KB, VB, kt);
        step(KB, VB, KA, VA, kt + 1);
    }

    lsA += __shfl_xor(lsA, 16); lsA += __shfl_xor(lsA, 32);
    lsB += __shfl_xor(lsB, 16); lsB += __shfl_xor(lsB, 32);
    const float invA = 1.f / lsA, invB = 1.f / lsB;
    const size_t cbA = ((size_t)(bb * 1024 + qA)) * 768 + hh * 64;
    const size_t cbB = ((size_t)(bb * 1024 + qB)) * 768 + hh * 64;
    #pragma unroll
    for (int dt = 0; dt < 4; ++dt) {
        u16 h4[4];
        #pragma unroll
        for (int r = 0; r < 4; ++r) h4[r] = f2bf(oA[dt][r] * invA);
        size_t co = cbA + dt * 16 + 4 * lg;
        *(uint2*)&ch[co] = make_uint2((uint32_t)h4[0] | ((uint32_t)h4[1] << 16),
                                      (uint32_t)h4[2] | ((uint32_t)h4[3] << 16));
        #pragma unroll
        for (int r = 0; r < 4; ++r) h4[r] = f2bf(oB[dt][r] * invB);
        co = cbB + dt * 16 + 4 * lg;
        *(uint2*)&ch[co] = make_uint2((uint32_t)h4[0] | ((uint32_t)h4[1] << 16),
                                      (uint32_t)h4[2] | ((uint32_t)h4[3] << 16));
    }
}

// ------------------------------------------------------------------- host

extern "C" void kernel_launch(void* const* d_in, const int* in_sizes, int n_in,
                              void* d_out, int out_size, void* d_ws, size_t ws_size,
                              hipStream_t stream) {
    const float* x0     = (const float*)d_in[0];
    const float* aproj  = (const float*)d_in[1];
    const float* mproj  = (const float*)d_in[2];
    const float* Wqkv   = (const float*)d_in[3];
    const float* Wo     = (const float*)d_in[4];
    const float* Wm1    = (const float*)d_in[5];
    const float* Wm2    = (const float*)d_in[6];
    const float* ascale = (const float*)d_in[7];
    const float* mscale = (const float*)d_in[8];
    const float* lns    = (const float*)d_in[9];
    float* out = (float*)d_out;
    char*  base = (char*)d_ws;

    float* p1  = (float*)base;
    float* p2  = p1 + BTD;
    float* p3  = p2 + BTD;
    u16*   xnh = (u16*)(base + 12 * BTD);
    u16*   wt0 = (u16*)(base + 14 * BTD);
    u16*   wt1 = wt0 + (size_t)2304 * 768;
    u16*   wt2 = wt1 + (size_t)768 * 768;
    u16*   wt3 = wt2 + (size_t)3072 * 768;
    char*  QB  = (char*)(wt3 + (size_t)768 * 3072);
    u16* qh   = (u16*)QB;        // slot 0
    u16* ql   = qh  + BTD;       // slot 1
    u16* kh   = ql  + BTD;       // slot 2
    u16* vh   = kh  + BTD;       // slot 3
    u16* vth  = vh  + BTD;       // slot 4
    u16* ctxh = vh;              // vh dead after vt_transpose
    u16* midh = qh;              // spans slots 0-3 (q/k/v dead after Wo)

    float* pb[3] = {p1, p2, p3};
    const float* L[5] = {x0, nullptr, nullptr, nullptr, nullptr};
    int nL = 1;
    float* partial_w = nullptr;
    int pidx = 0;

    auto launch_agg = [&](const float* qvec, const float* lnsl) {
        const float* a = L[0];
        const float* b = (nL > 1) ? L[1] : nullptr;
        const float* c = (nL > 2) ? L[2] : nullptr;
        const float* d = (nL > 3) ? L[3] : nullptr;
        const float* e = (nL > 4) ? L[4] : nullptr;
        switch (nL) {
        case 1: agg_norm_kernel<1><<<dim3(ROWS), 256, 0, stream>>>(a, b, c, d, e, qvec, lnsl, xnh); break;
        case 2: agg_norm_kernel<2><<<dim3(ROWS), 256, 0, stream>>>(a, b, c, d, e, qvec, lnsl, xnh); break;
        case 3: agg_norm_kernel<3><<<dim3(ROWS), 256, 0, stream>>>(a, b, c, d, e, qvec, lnsl, xnh); break;
        case 4: agg_norm_kernel<4><<<dim3(ROWS), 256, 0, stream>>>(a, b, c, d, e, qvec, lnsl, xnh); break;
        default: agg_norm_kernel<5><<<dim3(ROWS), 256, 0, stream>>>(a, b, c, d, e, qvec, lnsl, xnh); break;
        }
    };

    for (int l = 0; l < NLAYER; ++l) {
        // ---- all 4 weight transposes in one dispatch
        transpose_all<<<dim3(6912), 256, 0, stream>>>(
            Wqkv + (size_t)l * D_MODEL * 3 * D_MODEL,
            Wo   + (size_t)l * D_MODEL * D_MODEL,
            Wm1  + (size_t)l * D_MODEL * 4 * D_MODEL,
            Wm2  + (size_t)l * 4 * D_MODEL * D_MODEL,
            wt0, wt1, wt2, wt3);

        // ---- attention-path aggregate (reads OLD partial) -> xn (bf16)
        launch_agg(aproj + (size_t)l * D_MODEL, lns + l);

        // ---- block boundary (no fill: Wo EPI=4 initializes the new partial)
        const bool boundary = ((l & 1) == 0);
        if (boundary) {
            float* np = (pidx < 3) ? pb[pidx] : out;
            ++pidx;
            partial_w = np;
            L[nL++] = np;
        }

        // ---- QKV GEMM -> head-major q (hi/lo), k/v (hi)
        gemm_bf1<3, 128><<<dim3(3 * D_MODEL / 128, ROWS / 128), 256, 0, stream>>>(
            xnh, wt0, nullptr, nullptr, nullptr,
            ROWS, 3 * D_MODEL, D_MODEL, qh, ql, kh, vh);

        // ---- V transpose (hi only) -> vth
        vt_transpose<<<dim3(T_SEQ / 32, HDIM / 32, B_BATCH * NHEAD), 256, 0, stream>>>(
            vh, vth);

        // ---- flash attention -> ctx (single bf16, aliases vh)
        flash16<<<dim3(768), 256, 0, stream>>>(qh, ql, kh, vth, ctxh);

        // ---- Wo GEMM: partial (=|+=) attn_scale * (ctx @ Wo)
        if (boundary)
            gemm_bf1<4, 64><<<dim3(D_MODEL / 64, ROWS / 128), 256, 0, stream>>>(
                ctxh, wt1, partial_w, nullptr,
                ascale + (size_t)l * D_MODEL, ROWS, D_MODEL, D_MODEL,
                nullptr, nullptr, nullptr, nullptr);
        else
            gemm_bf1<2, 64><<<dim3(D_MODEL / 64, ROWS / 128), 256, 0, stream>>>(
                ctxh, wt1, partial_w, nullptr,
                ascale + (size_t)l * D_MODEL, ROWS, D_MODEL, D_MODEL,
                nullptr, nullptr, nullptr, nullptr);

        // ---- mlp-path aggregate (reads NEW partial) -> xn (bf16)
        launch_agg(mproj + (size_t)l * D_MODEL, lns + l);

        // ---- MLP: mid = gelu(xn @ Wm1) bf16; partial += mscale*(mid @ Wm2)
        gemm_bf1<1, 128><<<dim3(4 * D_MODEL / 128, ROWS / 128), 256, 0, stream>>>(
            xnh, wt2, nullptr, midh,
            nullptr, ROWS, 4 * D_MODEL, D_MODEL,
            nullptr, nullptr, nullptr, nullptr);
        gemm_bf1<2, 64><<<dim3(D_MODEL / 64, ROWS / 128), 256, 0, stream>>>(
            midh, wt3, partial_w, nullptr,
            mscale + (size_t)l * D_MODEL, ROWS, D_MODEL, 4 * D_MODEL,
            nullptr, nullptr, nullptr, nullptr);
    }
}